// Round 7
// baseline (73.058 us; speedup 1.0000x reference)
//
#include <hip/hip_runtime.h>

// ConvCapsuleLayer: fp16 MFMA conv GEMM + fused routing.
// r7: M=32 (4 w-pos) x N=256 per block, 256 thr. Wave = 32x64 tile -> acc = 2x f32x16
// (32 AGPR). LDS 20480 B -> 8 blocks/CU by LDS; residency register-bound ~5-6 waves/SIMD.
// PO2 staging decode, ii-stride 272B (bank spread), swizzled fp16 votes.

typedef __attribute__((ext_vector_type(8))) _Float16 f16x8;
typedef __attribute__((ext_vector_type(16))) float f32x16;

__device__ __forceinline__ unsigned short f2h(float x) {
  union { _Float16 h; unsigned short u; } v;
  v.h = (_Float16)x;
  return v.u;
}

// W[5][5][16][256] f32 -> wsh fp16 [khkw 25][ch 256][ia 16]
__global__ __launch_bounds__(256) void wprep_kernel(
    const float* __restrict__ W, unsigned short* __restrict__ wsh) {
  int t = blockIdx.x * 256 + threadIdx.x;      // 102400 total
  int khkw = t >> 12;
  int rem  = t & 4095;
  int ch = rem >> 4, ia = rem & 15;
  wsh[t] = f2h(W[khkw * 4096 + ia * 256 + ch]);
}

// Bank swizzle for votes LDS: XOR byte bits 4-6 with (ch>>3)&7.
#define VSWZ(byteoff, ch) ((byteoff) ^ ((((ch) >> 3) & 7) << 4))

// LDS map (20480 B):
//   conv phase:  X fp16 [kh 5][ii 8, stride 272B][wl 8][ia 16] = 10880 B @0
//   routing:     votesH fp16 [w 4][ch 256][ii 8] swizzled = 16384 @0 (aliases X)
//                actH   fp16 [w 4][ch 256]        = 2048 @16384
//                logitL f32  [c 8][w 4][ii 8]     = 1024 @18432
//                routeF f32  [w 4][c 8][ii 8]     = 1024 @19456
__global__ __launch_bounds__(256, 4) void capsconv_mfma_kernel(
    const float* __restrict__ inp,            // [16][32][32][8][16] f32
    const unsigned short* __restrict__ wsh,   // [25][256][16] fp16
    const float* __restrict__ bias,           // [256] f32
    float* __restrict__ out)                  // [16][32][32][256] f32
{
  __shared__ char smem[20480];
  const _Float16* wshh = (const _Float16*)wsh;
  char* votesB = smem;
  _Float16* actH   = (_Float16*)(smem + 16384);
  float*    logitL = (float*)(smem + 18432);
  float*    routeF = (float*)(smem + 19456);

  const int tid  = threadIdx.x;
  const int wid  = tid >> 6;          // wave 0..3 -> ch quarter
  const int lane = tid & 63;
  const int sub  = lane >> 5;
  const int ln31 = lane & 31;

  const int bid = blockIdx.x;         // 4096 = ((bb*32 + h)*8 + wq)
  const int wq = bid & 7;
  const int h  = (bid >> 3) & 31;
  const int bb = bid >> 8;
  const int i_src  = bb >> 1;         // TF reshape scramble (verified r1/r4)
  const int b_base = (bb & 1) * 8;

  // ---------------- stage 5 X rows, PO2 decode (1280 quads) ----------------
  #pragma unroll
  for (int s = 0; s < 5; ++s) {
    int e = tid + s * 256;
    int kh  = e >> 8;
    int ii  = (e >> 5) & 7;
    int wl  = (e >> 2) & 7;
    int iaq = e & 3;
    int hh = h + kh - 2;
    int wsrc = wq * 4 + wl - 2;
    float4 v = make_float4(0.f, 0.f, 0.f, 0.f);
    if ((unsigned)hh < 32u && (unsigned)wsrc < 32u)
      v = *(const float4*)(inp +
          ((((size_t)(b_base + ii) * 32 + hh) * 32 + wsrc) * 8 + i_src) * 16 + iaq * 4);
    union { _Float16 hx[4]; unsigned long long u; } pk;
    pk.hx[0] = (_Float16)v.x; pk.hx[1] = (_Float16)v.y;
    pk.hx[2] = (_Float16)v.z; pk.hx[3] = (_Float16)v.w;
    *(unsigned long long*)(smem + kh * 2176 + ii * 272 + wl * 32 + iaq * 8) = pk.u;
  }
  __syncthreads();

  // ---------------- conv: 25 taps, barrier-free ----------------
  f32x16 acc[2];
  #pragma unroll
  for (int nt = 0; nt < 2; ++nt)
    #pragma unroll
    for (int e = 0; e < 16; ++e) acc[nt][e] = 0.f;

  #pragma unroll 1
  for (int kh = 0; kh < 5; ++kh) {
    #pragma unroll
    for (int kw = 0; kw < 5; ++kw) {
      // rows r = ln31: w_local = r>>3, ii = r&7
      f16x8 afrag = *(const f16x8*)(smem + kh * 2176 + (ln31 & 7) * 272 +
                                    ((ln31 >> 3) + kw) * 32 + sub * 16);
      #pragma unroll
      for (int nt = 0; nt < 2; ++nt) {
        int ch = wid * 64 + nt * 32 + ln31;
        f16x8 bfrag = *(const f16x8*)(wshh + (size_t)(kh * 5 + kw) * 4096 + ch * 16 + sub * 8);
        acc[nt] = __builtin_amdgcn_mfma_f32_32x32x16_f16(afrag, bfrag, acc[nt], 0, 0, 0);
      }
    }
  }

  // ---------------- votes -> LDS fp16 [w][ch][ii], swizzled ----------------
  __syncthreads();   // X region dead; votes alias it
  #pragma unroll
  for (int nt = 0; nt < 2; ++nt) {
    int ch = wid * 64 + nt * 32 + ln31;
    #pragma unroll
    for (int w = 0; w < 4; ++w) {
      // regs 4w..4w+3: row = t + 8w + 4sub -> ii = t + 4sub
      union { _Float16 hx[4]; unsigned long long u; } pk;
      #pragma unroll
      for (int t = 0; t < 4; ++t) pk.hx[t] = (_Float16)acc[nt][w * 4 + t];
      int byte = (w * 256 + ch) * 16 + sub * 8;
      *(unsigned long long*)(votesB + VSWZ(byte, ch)) = pk.u;
    }
  }
  __syncthreads();

  // ---------------- routing ----------------
  const int c_own = tid >> 5;
  const float bv = bias[tid];
  const int ag_w = tid >> 6;          // agreement task: (w, c) x 8 g-lanes
  const int ag_c = (tid >> 3) & 7;
  const int ag_g = tid & 7;

  // cache this thread's 4 vote fragments (ch = tid) in registers
  f16x8 vreg[4];
  #pragma unroll
  for (int w = 0; w < 4; ++w)
    vreg[w] = *(const f16x8*)(votesB + VSWZ((w * 256 + tid) * 16, tid));

  #pragma unroll 1
  for (int rt = 0; rt < 3; ++rt) {
    if (rt > 0) {
      if (tid < 32) {                 // softmax over c per (w, ii)
        int wv = tid >> 3, ii = tid & 7;
        float l[8];
        #pragma unroll
        for (int c = 0; c < 8; ++c) l[c] = logitL[(c * 4 + wv) * 8 + ii];
        float mx = fmaxf(fmaxf(fmaxf(l[0], l[1]), fmaxf(l[2], l[3])),
                         fmaxf(fmaxf(l[4], l[5]), fmaxf(l[6], l[7])));
        float den = 0.f;
        #pragma unroll
        for (int c = 0; c < 8; ++c) den += __expf(l[c] - mx);
        float inv = 1.f / den;
        #pragma unroll
        for (int c = 0; c < 8; ++c)
          routeF[(wv * 8 + c) * 8 + ii] = __expf(l[c] - mx) * inv;
      }
      __syncthreads();
    }
    // weighted sum + squash; thread owns ch = tid
    #pragma unroll
    for (int w = 0; w < 4; ++w) {
      float pre = bv;
      if (rt == 0) {
        float s = 0.f;
        #pragma unroll
        for (int i = 0; i < 8; ++i) s += (float)vreg[w][i];
        pre = fmaf(0.125f, s, pre);
      } else {
        const float* rp = routeF + (w * 8 + c_own) * 8;   // broadcast read
        #pragma unroll
        for (int i = 0; i < 8; ++i) pre = fmaf(rp[i], (float)vreg[w][i], pre);
      }
      float nsq = pre * pre;
      #pragma unroll
      for (int m = 16; m >= 1; m >>= 1) nsq += __shfl_xor(nsq, m, 64);
      float av = pre * (sqrtf(nsq) / (1.f + nsq));
      if (rt == 2)
        out[((size_t)((bb * 32 + h) * 32 + wq * 4 + w)) * 256 + tid] = av;
      else
        actH[w * 256 + tid] = (_Float16)av;
    }
    if (rt < 2) {
      __syncthreads();
      // agreement: dot(vote, act) over 32 atoms; (w,c) split over 8 g-lanes
      float dot8[8];
      #pragma unroll
      for (int i = 0; i < 8; ++i) dot8[i] = 0.f;
      #pragma unroll
      for (int j0 = 0; j0 < 4; ++j0) {
        int a = ag_g * 4 + ((j0 + ag_c) & 3);       // c-staggered
        int ch = ag_c * 32 + a;
        int byte = (ag_w * 256 + ch) * 16;
        f16x8 vp = *(const f16x8*)(votesB + VSWZ(byte, ch));
        float av = (float)actH[ag_w * 256 + ch];
        #pragma unroll
        for (int ii = 0; ii < 8; ++ii) dot8[ii] = fmaf((float)vp[ii], av, dot8[ii]);
      }
      #pragma unroll
      for (int ii = 0; ii < 8; ++ii) {
        dot8[ii] += __shfl_xor(dot8[ii], 1, 64);
        dot8[ii] += __shfl_xor(dot8[ii], 2, 64);
        dot8[ii] += __shfl_xor(dot8[ii], 4, 64);
      }
      if (ag_g == 0) {
        #pragma unroll
        for (int ii = 0; ii < 8; ++ii) {
          int idx = (ag_c * 4 + ag_w) * 8 + ii;
          if (rt == 0) logitL[idx] = dot8[ii];
          else         logitL[idx] += dot8[ii];
        }
      }
      __syncthreads();
    }
  }
}

extern "C" void kernel_launch(void* const* d_in, const int* in_sizes, int n_in,
                              void* d_out, int out_size, void* d_ws, size_t ws_size,
                              hipStream_t stream) {
  (void)in_sizes; (void)n_in; (void)ws_size; (void)out_size;
  const float* inp  = (const float*)d_in[0];
  const float* W    = (const float*)d_in[1];
  const float* bv   = (const float*)d_in[2];
  float* out        = (float*)d_out;
  unsigned short* wsh = (unsigned short*)d_ws;   // 204800 B used

  hipLaunchKernelGGL(wprep_kernel, dim3(400), dim3(256), 0, stream, W, wsh);
  hipLaunchKernelGGL(capsconv_mfma_kernel, dim3(4096), dim3(256), 0, stream,
                     inp, wsh, bv, out);
}